// Round 4
// baseline (4605.434 us; speedup 1.0000x reference)
//
#include <hip/hip_runtime.h>
#include <hip/hip_bf16.h>

// Problem constants (B, N, C fixed by reference)
#define BB 8
#define NN 2048
#define CC 256
#define GG 64        // C / NGRP groups of 4 channels
#define QQ 8

typedef unsigned short u16;

static __device__ __forceinline__ float b2f(u16 u) {
  union { unsigned int i; float f; } cv; cv.i = ((unsigned int)u) << 16; return cv.f;
}
static __device__ __forceinline__ u16 f2b(float f) {
  union { __hip_bfloat16 h; u16 u; } cv; cv.h = __float2bfloat16(f); return cv.u;
}
// dtype-flexible scalar load: flag ? float32 : bf16
static __device__ __forceinline__ float ldin(const void* p, size_t i, bool f32) {
  return f32 ? ((const float*)p)[i] : b2f(((const u16*)p)[i]);
}

// ---------------------------------------------------------------------------
// dtype detection (bf16 vs f32 inputs) — robust either way.
// ---------------------------------------------------------------------------
__global__ __launch_bounds__(256) void detect_kernel(const u16* __restrict__ sc,
                                                     int* __restrict__ flag)
{
  __shared__ int sh;
  if (threadIdx.x == 0) sh = 0;
  __syncthreads();
  int cnt = 0;
  for (int i = threadIdx.x; i < 2048; i += 256) {
    u16 w = sc[2 * i];
    int e = (w >> 7) & 0xFF;
    if (e >= 100 && e <= 130) cnt++;
  }
  atomicAdd(&sh, cnt);
  __syncthreads();
  if (threadIdx.x == 0) *flag = (sh < 1024) ? 1 : 0;   // 1 => float32 inputs
}

// ---------------------------------------------------------------------------
// K_f32[bl,i,j] = 0.5*(sc[b,i,j]+sc[b,j,i]) * sigmoid(dot(U[i],U[j]))
// bl = b - grp*4 (4 batches per phase; K reused across all Q steps)
// ---------------------------------------------------------------------------
__global__ __launch_bounds__(256) void build_k_kernel(
    const void* __restrict__ sc, const void* __restrict__ U,
    float* __restrict__ Kf, const int* __restrict__ flagp, int grp)
{
  const bool f32 = (*flagp != 0);
  const int bl = blockIdx.z;            // 0..3
  const int b  = grp * 4 + bl;
  const int i0 = blockIdx.y * 32;
  const int j0 = blockIdx.x * 32;
  const int tx = threadIdx.x;   // 0..31
  const int ty = threadIdx.y;   // 0..7
  const int t  = ty * 32 + tx;

  __shared__ float Ui[32][17];
  __shared__ float Uj[32][17];
  __shared__ float st[32][33];

  for (int s = t; s < 512; s += 256) {
    int rr = s >> 4, kk = s & 15;
    Ui[rr][kk] = ldin(U, (size_t)(i0 + rr) * 16 + kk, f32);
    Uj[rr][kk] = ldin(U, (size_t)(j0 + rr) * 16 + kk, f32);
  }
  const size_t scb = (size_t)b * NN * NN;
  for (int jj = ty; jj < 32; jj += 8)
    st[jj][tx] = ldin(sc, scb + (size_t)(j0 + jj) * NN + i0 + tx, f32);
  __syncthreads();

  const size_t kfb = (size_t)bl * NN * NN;
  for (int ii = ty; ii < 32; ii += 8) {
    float dot = 0.f;
    #pragma unroll
    for (int k = 0; k < 16; k++) dot += Ui[ii][k] * Uj[tx][k];
    float A = 1.0f / (1.0f + expf(-dot));
    float d = ldin(sc, scb + (size_t)(i0 + ii) * NN + j0 + tx, f32);
    Kf[kfb + (size_t)(i0 + ii) * NN + j0 + tx] = 0.5f * (d + st[tx][ii]) * A;
  }
}

// ---------------------------------------------------------------------------
// GroupNorm stats over y[b, 4g:4g+4, :]  (8192 elems per (b,g))
// ---------------------------------------------------------------------------
__global__ __launch_bounds__(256) void gn_stats_kernel(
    const void* __restrict__ y, float* __restrict__ murs,
    const int* __restrict__ flagp)
{
  const bool f32 = (*flagp != 0);
  const int bg = blockIdx.x;                    // b*64 + g
  float s = 0.f, ss = 0.f;
  if (f32) {
    const float* base = (const float*)y + (size_t)bg * 4 * NN;
    for (int i = threadIdx.x; i < 2048; i += 256) {
      float4 v = *(const float4*)(base + (size_t)i * 4);
      s  += v.x + v.y + v.z + v.w;
      ss += v.x*v.x + v.y*v.y + v.z*v.z + v.w*v.w;
    }
  } else {
    const u16* base = (const u16*)y + (size_t)bg * 4 * NN;
    for (int i = threadIdx.x; i < 2048; i += 256) {
      ushort4 v = *(const ushort4*)(base + (size_t)i * 4);
      float f0 = b2f(v.x), f1 = b2f(v.y), f2 = b2f(v.z), f3 = b2f(v.w);
      s  += f0 + f1 + f2 + f3;
      ss += f0*f0 + f1*f1 + f2*f2 + f3*f3;
    }
  }
  #pragma unroll
  for (int off = 32; off > 0; off >>= 1) {
    s  += __shfl_down(s, off, 64);
    ss += __shfl_down(ss, off, 64);
  }
  __shared__ float sh[8];
  const int w = threadIdx.x >> 6, ln = threadIdx.x & 63;
  if (ln == 0) { sh[w * 2] = s; sh[w * 2 + 1] = ss; }
  __syncthreads();
  if (threadIdx.x == 0) {
    float S  = sh[0] + sh[2] + sh[4] + sh[6];
    float SS = sh[1] + sh[3] + sh[5] + sh[7];
    float mu  = S / 8192.0f;
    float var = SS / 8192.0f - mu * mu;
    murs[bg * 2]     = mu;
    murs[bg * 2 + 1] = 1.0f / sqrtf(fmaxf(var, 0.f) + 1e-5f);
  }
}

// ---------------------------------------------------------------------------
// y_t[b,n,c] = sphere( GN(y)[b,c,n] * w + bias ), groups of 4 channels (f32)
// ---------------------------------------------------------------------------
__global__ __launch_bounds__(256) void y_tf_kernel(
    const void* __restrict__ y, const float* __restrict__ murs,
    const void* __restrict__ gw, const void* __restrict__ gb,
    float* __restrict__ yt, const int* __restrict__ flagp)
{
  const bool f32 = (*flagp != 0);
  const int b = blockIdx.y;
  const int n = blockIdx.x * 64 + threadIdx.x;
  for (int g = threadIdx.y; g < GG; g += 4) {
    float mu = murs[(b * GG + g) * 2];
    float rs = murs[(b * GG + g) * 2 + 1];
    float v[4];
    #pragma unroll
    for (int k = 0; k < 4; k++) {
      int c = 4 * g + k;
      float val = (ldin(y, ((size_t)b * CC + c) * NN + n, f32) - mu) * rs;
      v[k] = val * ldin(gw, c, f32) + ldin(gb, c, f32);
    }
    float n2 = v[0]*v[0] + v[1]*v[1] + v[2]*v[2] + v[3]*v[3];
    float scl = 1.0f / sqrtf(fmaxf(n2, 1e-6f));
    float4 o; o.x = v[0]*scl; o.y = v[1]*scl; o.z = v[2]*scl; o.w = v[3]*scl;
    *(float4*)(yt + ((size_t)b * NN + n) * CC + 4 * g) = o;
  }
}

// ---------------------------------------------------------------------------
// x init: sphere-normalize x -> f32 state buffer A
// ---------------------------------------------------------------------------
__global__ __launch_bounds__(256) void x_init_kernel(
    const void* __restrict__ x, float* __restrict__ xst,
    const int* __restrict__ flagp)
{
  const bool f32 = (*flagp != 0);
  const int b = blockIdx.y;
  const int n = blockIdx.x * 64 + threadIdx.x;
  for (int g = threadIdx.y; g < GG; g += 4) {
    size_t idx = ((size_t)b * NN + n) * CC + 4 * g;
    float v[4];
    if (f32) {
      float4 u4 = *(const float4*)((const float*)x + idx);
      v[0] = u4.x; v[1] = u4.y; v[2] = u4.z; v[3] = u4.w;
    } else {
      ushort4 u = *(const ushort4*)((const u16*)x + idx);
      v[0] = b2f(u.x); v[1] = b2f(u.y); v[2] = b2f(u.z); v[3] = b2f(u.w);
    }
    float n2 = v[0]*v[0] + v[1]*v[1] + v[2]*v[2] + v[3]*v[3];
    float scl = 1.0f / sqrtf(fmaxf(n2, 1e-6f));
    float4 o; o.x = v[0]*scl; o.y = v[1]*scl; o.z = v[2]*scl; o.w = v[3]*scl;
    *(float4*)(xst + idx) = o;
  }
}

// ---------------------------------------------------------------------------
// Fused f32 GEMM + Kuramoto step.
//   coup[n,c] = sum_m K[bl,n,m] * xc[b,m,c]   then per-group step -> xn, out
// BM=128, BN=64, BK=16; 128 threads (2 waves), 8x8 per thread.
// Grid: (CC/64, NN/128, 4) = (4, 16, 4) = 256 blocks -> 2 blocks/CU, 4 waves/CU.
// Thread tile 8x8: LDS bytes/FMA halved vs 4x4 (the r3 bottleneck: LDS pipe
// at ~128 B/cyc limited VALUBusy to 51%).
// ---------------------------------------------------------------------------
__global__ __launch_bounds__(128) void gemm_step_kernel(
    const float* __restrict__ Kf, const float* __restrict__ xc,
    float* __restrict__ xn, const float* __restrict__ yt,
    const void* __restrict__ omega, const void* __restrict__ gamma,
    void* __restrict__ outbase, size_t qoff,
    const int* __restrict__ flagp, int grp)
{
  const int bl = blockIdx.z;
  const int b  = grp * 4 + bl;
  const int m0 = blockIdx.y * 128;
  const int c0 = blockIdx.x * 64;
  const float* A  = Kf + (size_t)bl * NN * NN;
  const float* Bx = xc + (size_t)b  * NN * CC;

  __shared__ float As[16][132];   // [k][m], pad 128->132
  __shared__ float Bs[16][68];    // [k][c], pad 64->68

  const int t  = threadIdx.x;     // 0..127
  const int tx = t & 7;           // col octet  (8 cols)
  const int ty = t >> 3;          // row octet  (0..15, 8 rows each)

  // staging indices
  const int ar = t >> 2;          // 0..31  (A row within 32-row slab)
  const int ak = (t & 3) * 4;     // 0,4,8,12
  const int bk = t >> 3;          // 0..15  (B k)
  const int bc = (t & 7) * 8;     // B col octet

  float acc[8][8];
  #pragma unroll
  for (int i = 0; i < 8; i++)
    #pragma unroll
    for (int j = 0; j < 8; j++) acc[i][j] = 0.f;

  float4 pa[4], pb[2];
  #pragma unroll
  for (int i = 0; i < 4; i++)
    pa[i] = *(const float4*)(A + (size_t)(m0 + i * 32 + ar) * NN + ak);
  pb[0] = *(const float4*)(Bx + (size_t)bk * CC + c0 + bc);
  pb[1] = *(const float4*)(Bx + (size_t)bk * CC + c0 + bc + 4);

  for (int k0 = 0; k0 < NN; k0 += 16) {
    __syncthreads();
    #pragma unroll
    for (int i = 0; i < 4; i++) {
      As[ak + 0][i * 32 + ar] = pa[i].x;
      As[ak + 1][i * 32 + ar] = pa[i].y;
      As[ak + 2][i * 32 + ar] = pa[i].z;
      As[ak + 3][i * 32 + ar] = pa[i].w;
    }
    *(float4*)&Bs[bk][bc]     = pb[0];
    *(float4*)&Bs[bk][bc + 4] = pb[1];
    __syncthreads();
    const int kn = k0 + 16;
    if (kn < NN) {
      #pragma unroll
      for (int i = 0; i < 4; i++)
        pa[i] = *(const float4*)(A + (size_t)(m0 + i * 32 + ar) * NN + kn + ak);
      pb[0] = *(const float4*)(Bx + (size_t)(kn + bk) * CC + c0 + bc);
      pb[1] = *(const float4*)(Bx + (size_t)(kn + bk) * CC + c0 + bc + 4);
    }
    #pragma unroll
    for (int k = 0; k < 16; k++) {
      float4 a0 = *(const float4*)&As[k][ty * 8];
      float4 a1 = *(const float4*)&As[k][ty * 8 + 4];
      float4 b0 = *(const float4*)&Bs[k][tx * 8];
      float4 b1 = *(const float4*)&Bs[k][tx * 8 + 4];
      float av[8] = {a0.x, a0.y, a0.z, a0.w, a1.x, a1.y, a1.z, a1.w};
      float bv[8] = {b0.x, b0.y, b0.z, b0.w, b1.x, b1.y, b1.z, b1.w};
      #pragma unroll
      for (int i = 0; i < 8; i++)
        #pragma unroll
        for (int j = 0; j < 8; j++)
          acc[i][j] += av[i] * bv[j];
    }
  }

  // ---- fused Kuramoto step epilogue (thread owns 8 rows x 2 groups) ----
  const bool f32o = (*flagp != 0);
  const float gm = ldin(gamma, 0, f32o);
  const int g0 = (c0 >> 2) + 2 * tx;
  float om[4];
  om[0] = fabsf(ldin(omega, 2 * g0,     f32o));
  om[1] = fabsf(ldin(omega, 2 * g0 + 1, f32o));
  om[2] = fabsf(ldin(omega, 2 * g0 + 2, f32o));
  om[3] = fabsf(ldin(omega, 2 * g0 + 3, f32o));

  #pragma unroll
  for (int i = 0; i < 8; i++) {
    const int n = m0 + ty * 8 + i;
    const size_t idx = ((size_t)b * NN + n) * CC + c0 + tx * 8;
    #pragma unroll
    for (int h = 0; h < 2; h++) {
      float4 x4 = *(const float4*)(xc + idx + 4 * h);
      float4 y4 = *(const float4*)(yt + idx + 4 * h);
      float xv[4] = {x4.x, x4.y, x4.z, x4.w};
      float f[4]  = {acc[i][4*h+0] + y4.x, acc[i][4*h+1] + y4.y,
                     acc[i][4*h+2] + y4.z, acc[i][4*h+3] + y4.w};
      float sim = xv[0]*f[0] + xv[1]*f[1] + xv[2]*f[2] + xv[3]*f[3];
      float o0 = om[2*h], o1 = om[2*h+1];
      float d0 =  o0 * xv[1] + (f[0] - sim * xv[0]);
      float d1 = -o0 * xv[0] + (f[1] - sim * xv[1]);
      float d2 =  o1 * xv[3] + (f[2] - sim * xv[2]);
      float d3 = -o1 * xv[2] + (f[3] - sim * xv[3]);
      float v0 = xv[0] + gm * d0, v1 = xv[1] + gm * d1;
      float v2 = xv[2] + gm * d2, v3 = xv[3] + gm * d3;
      float n2 = v0*v0 + v1*v1 + v2*v2 + v3*v3;
      float scl = 1.0f / sqrtf(fmaxf(n2, 1e-6f));
      float z0 = v0*scl, z1 = v1*scl, z2 = v2*scl, z3 = v3*scl;
      float4 o; o.x = z0; o.y = z1; o.z = z2; o.w = z3;
      *(float4*)(xn + idx + 4 * h) = o;
      if (f32o) {
        *(float4*)((float*)outbase + qoff + idx + 4 * h) = o;
      } else {
        ushort4 ob; ob.x = f2b(z0); ob.y = f2b(z1); ob.z = f2b(z2); ob.w = f2b(z3);
        *(ushort4*)((u16*)outbase + qoff + idx + 4 * h) = ob;
      }
    }
  }
}

// ---------------------------------------------------------------------------
extern "C" void kernel_launch(void* const* d_in, const int* in_sizes, int n_in,
                              void* d_out, int out_size, void* d_ws, size_t ws_size,
                              hipStream_t stream) {
  const void* x     = d_in[0];
  const void* y     = d_in[1];
  const void* sc    = d_in[2];
  const void* U     = d_in[3];
  const void* omega = d_in[4];
  const void* gw    = d_in[5];
  const void* gb    = d_in[6];
  const void* gamma = d_in[7];
  // d_in[8] = Q (int32) — fixed at 8 by the problem setup.
  char* ws = (char*)d_ws;

  // Workspace layout (~117.5 MB, proven safe in round 3)
  const size_t BNC = (size_t)BB * NN * CC;             // 4,194,304
  float* Kf   = (float*)(ws);                          // 4 batches f32: 67,108,864 B
  float* yt   = (float*)(ws + 67108864);               // 16,777,216 B
  float* xstA = (float*)(ws + 83886080);               // 16,777,216 B
  float* xstB = (float*)(ws + 100663296);              // 16,777,216 B
  float* murs = (float*)(ws + 117440512);              // 4 KB
  int*   flag = (int*)  (ws + 117444608);              // 4 B

  detect_kernel<<<dim3(1), dim3(256), 0, stream>>>((const u16*)sc, flag);
  gn_stats_kernel<<<dim3(512), dim3(256), 0, stream>>>(y, murs, flag);
  y_tf_kernel<<<dim3(32, 8), dim3(64, 4), 0, stream>>>(y, murs, gw, gb, yt, flag);
  x_init_kernel<<<dim3(32, 8), dim3(64, 4), 0, stream>>>(x, xstA, flag);

  for (int grp = 0; grp < 2; grp++) {
    build_k_kernel<<<dim3(64, 64, 4), dim3(32, 8), 0, stream>>>(sc, U, Kf, flag, grp);
    float* cur = xstA;   // QQ even => pointer returns to xstA after each phase,
    float* nxt = xstB;   // so phase 1 reads batches 4-7 untouched in xstA.
    for (int q = 0; q < QQ; q++) {
      gemm_step_kernel<<<dim3(4, 16, 4), dim3(128), 0, stream>>>(
          Kf, cur, nxt, yt, omega, gamma, d_out, (size_t)q * BNC, flag, grp);
      float* tmp = cur; cur = nxt; nxt = tmp;
    }
  }
}